// Round 1
// baseline (85.391 us; speedup 1.0000x reference)
//
#include <hip/hip_runtime.h>

#define UNITS 2048
#define KDIM  204
#define T     5
#define BATCH 32

#define BPB   8      // b-rows per block
#define UPB   32     // u per block
#define ROWB  2064   // padded LDS row stride in bytes (16B aligned, 516 words ≡ 4 mod 32)

// decay powers, double-computed then rounded to float
#define PD1  0.951229424500714f     // exp(-0.05)
#define PD2  0.9048374180359595f    // exp(-0.10)
#define PD3  0.8607079764250578f    // exp(-0.15)
#define PD4  0.8187307530779818f    // exp(-0.20)
#define PD5  0.7788007830714049f    // exp(-0.25)
#define PA1  0.9950124791926823f    // exp(-0.005)
#define PA2  0.9900498337491681f    // exp(-0.010)
#define PA3  0.9851119396030626f    // exp(-0.015)
#define PA4  0.9801986733067553f    // exp(-0.020)
#define PA5  0.9753099120283326f    // exp(-0.025)
#define PAM1 1.0050125208594014f    // exp(+0.005)

// ---------------------------------------------------------------------------
// Pre-pass: pack z_buf0 (B,T,UNITS) float 0/1 into one byte per (b,u), bit t.
// ---------------------------------------------------------------------------
__global__ __launch_bounds__(256) void alif_pack(const float* __restrict__ zbuf,
                                                 unsigned char* __restrict__ zbyte) {
    int tid = blockIdx.x * 256 + threadIdx.x;   // 0 .. B*UNITS-1
    int u = tid & (UNITS - 1);
    int b = tid >> 11;                          // UNITS = 2^11
    unsigned v = 0;
#pragma unroll
    for (int t = 0; t < T; ++t) {
        float z = zbuf[((size_t)b * T + t) * UNITS + u];
        v |= (z > 0.5f ? 1u : 0u) << t;
    }
    zbyte[(size_t)b * UNITS + u] = (unsigned char)v;
}

// ---------------------------------------------------------------------------
// Main kernel: one thread per (b,u). i_rec via byte-gather from LDS bit table,
// then the full T=5 ALIF update (filters, spike, refractory, reset).
// ---------------------------------------------------------------------------
#define ACC(zz, ww)                                          \
    acc0 = fmaf((float)((zz)      & 1u), (ww), acc0);        \
    acc1 = fmaf((float)(((zz)>>1) & 1u), (ww), acc1);        \
    acc2 = fmaf((float)(((zz)>>2) & 1u), (ww), acc2);        \
    acc3 = fmaf((float)(((zz)>>3) & 1u), (ww), acc3);        \
    acc4 = fmaf((float)(((zz)>>4) & 1u), (ww), acc4);

__global__ __launch_bounds__(256) void alif_main(
    const float* __restrict__ inputs, const float* __restrict__ v0,
    const float* __restrict__ a0, const float* __restrict__ wv,
    const float* __restrict__ beta, const int* __restrict__ cols,
    const unsigned char* __restrict__ zbyte, float* __restrict__ out) {

    __shared__ unsigned char lds_z[BPB * ROWB];

    const int tid  = threadIdx.x;
    const int bx   = blockIdx.x;          // 0..255
    const int ublk = bx & 63;             // 64 u-blocks
    const int bblk = bx >> 6;             // 4 b-blocks
    const int u       = ublk * UPB + (tid & 31);
    const int b_local = tid >> 5;
    const int b       = bblk * BPB + b_local;

    // ---- stage 8 byte-rows (8 x 2048 B) into LDS with padded stride ----
    {
        const uint4* src = (const uint4*)(zbyte + (size_t)bblk * BPB * UNITS);
#pragma unroll
        for (int i = 0; i < 4; ++i) {
            int q = tid + 256 * i;        // 0..1023  (1024 uint4 = 16 KB)
            uint4 val = src[q];
            int row = q >> 7;             // 128 uint4 per 2048B row
            int col = (q & 127) << 4;     // byte offset in row
            *(uint4*)(&lds_z[row * ROWB + col]) = val;
        }
    }
    __syncthreads();

    const int rowoff = b_local * ROWB;

    // ---- i_rec: gather-MAC over K with bit table ----
    const int4*   cp = (const int4*)(cols + (size_t)u * KDIM);
    const float4* wp = (const float4*)(wv + (size_t)u * KDIM);
    float acc0 = 0.f, acc1 = 0.f, acc2 = 0.f, acc3 = 0.f, acc4 = 0.f;

    int4   c = cp[0];
    float4 w = wp[0];
#pragma unroll 3
    for (int kk = 0; kk < KDIM / 4 - 1; ++kk) {
        int4   cn = cp[kk + 1];
        float4 wn = wp[kk + 1];
        unsigned z0 = lds_z[rowoff + c.x];
        unsigned z1 = lds_z[rowoff + c.y];
        unsigned z2 = lds_z[rowoff + c.z];
        unsigned z3 = lds_z[rowoff + c.w];
        ACC(z0, w.x) ACC(z1, w.y) ACC(z2, w.z) ACC(z3, w.w)
        c = cn; w = wn;
    }
    {
        unsigned z0 = lds_z[rowoff + c.x];
        unsigned z1 = lds_z[rowoff + c.y];
        unsigned z2 = lds_z[rowoff + c.z];
        unsigned z3 = lds_z[rowoff + c.w];
        ACC(z0, w.x) ACC(z1, w.y) ACC(z2, w.z) ACC(z3, w.w)
    }

    // ---- ALIF update for T=5 ----
    const size_t base = ((size_t)b * T) * UNITS + u;
    float i0 = inputs[base + 0 * UNITS] + acc0;
    float i1 = inputs[base + 1 * UNITS] + acc1;
    float i2 = inputs[base + 2 * UNITS] + acc2;
    float i3 = inputs[base + 3 * UNITS] + acc3;
    float i4 = inputs[base + 4 * UNITS] + acc4;

    const float v0v = v0[(size_t)b * UNITS + u];
    const float a0v = a0[(size_t)b * UNITS + u];
    const float bet = beta[u];

    // filtered_i[t] = sum_{s<=t} DECAY^(t-s) * i_total[s]  (ascending s)
    float f0 = i0;
    float f1 = fmaf(PD1, i0, i1);
    float f2 = PD2 * i0; f2 = fmaf(PD1, i1, f2); f2 += i2;
    float f3 = PD3 * i0; f3 = fmaf(PD2, i1, f3); f3 = fmaf(PD1, i2, f3); f3 += i3;
    float f4 = PD4 * i0; f4 = fmaf(PD3, i1, f4); f4 = fmaf(PD2, i2, f4);
    f4 = fmaf(PD1, i3, f4); f4 += i4;

    float tv0 = fmaf(PD1, v0v, f0);
    float tv1 = fmaf(PD2, v0v, f1);
    float tv2 = fmaf(PD3, v0v, f2);
    float tv3 = fmaf(PD4, v0v, f3);
    float tv4 = fmaf(PD5, v0v, f4);

    float ta0 = PA1 * a0v;
    float ta1 = PA2 * a0v;
    float ta2 = PA3 * a0v;
    float ta3 = PA4 * a0v;
    float ta4 = PA5 * a0v;

    float vsc0 = tv0 - bet * ta0 - 1.0f;
    float vsc1 = tv1 - bet * ta1 - 1.0f;
    float vsc2 = tv2 - bet * ta2 - 1.0f;
    float vsc3 = tv3 - bet * ta3 - 1.0f;
    float vsc4 = tv4 - bet * ta4 - 1.0f;

    unsigned zr = (vsc0 > 0.f ? 1u : 0u) | (vsc1 > 0.f ? 2u : 0u) |
                  (vsc2 > 0.f ? 4u : 0u) | (vsc3 > 0.f ? 8u : 0u) |
                  (vsc4 > 0.f ? 16u : 0u);
    const unsigned zob = lds_z[rowoff + u];

    float zf[T];
#pragma unroll
    for (int t = 0; t < T; ++t) {
        bool raw     = (zr >> t) & 1u;
        bool blocked = ((zr & ((1u << t) - 1u)) != 0u) || ((zob >> (t + 1)) != 0u);
        zf[t] = (raw && !blocked) ? 1.0f : 0.0f;
    }

    // filtered_reset (DECAY kernel) and filtered_a_inc (DECAY_A^(t-s-1))
    float r0 = zf[0];
    float r1 = fmaf(PD1, zf[0], zf[1]);
    float r2 = PD2 * zf[0]; r2 = fmaf(PD1, zf[1], r2); r2 += zf[2];
    float r3 = PD3 * zf[0]; r3 = fmaf(PD2, zf[1], r3); r3 = fmaf(PD1, zf[2], r3); r3 += zf[3];
    float r4 = PD4 * zf[0]; r4 = fmaf(PD3, zf[1], r4); r4 = fmaf(PD2, zf[2], r4);
    r4 = fmaf(PD1, zf[3], r4); r4 += zf[4];

    float g0 = PAM1 * zf[0];
    float g1 = zf[0]; g1 = fmaf(PAM1, zf[1], g1);
    float g2 = PA1 * zf[0]; g2 += zf[1]; g2 = fmaf(PAM1, zf[2], g2);
    float g3 = PA2 * zf[0]; g3 = fmaf(PA1, zf[1], g3); g3 += zf[2]; g3 = fmaf(PAM1, zf[3], g3);
    float g4 = PA3 * zf[0]; g4 = fmaf(PA2, zf[1], g4); g4 = fmaf(PA1, zf[2], g4);
    g4 += zf[3]; g4 = fmaf(PAM1, zf[4], g4);

    const size_t BTU = (size_t)BATCH * T * UNITS;
    // z
    out[0 * BTU + base + 0 * UNITS] = zf[0];
    out[0 * BTU + base + 1 * UNITS] = zf[1];
    out[0 * BTU + base + 2 * UNITS] = zf[2];
    out[0 * BTU + base + 3 * UNITS] = zf[3];
    out[0 * BTU + base + 4 * UNITS] = zf[4];
    // v_buf
    out[1 * BTU + base + 0 * UNITS] = tv0 - r0;
    out[1 * BTU + base + 1 * UNITS] = tv1 - r1;
    out[1 * BTU + base + 2 * UNITS] = tv2 - r2;
    out[1 * BTU + base + 3 * UNITS] = tv3 - r3;
    out[1 * BTU + base + 4 * UNITS] = tv4 - r4;
    // a_buf
    out[2 * BTU + base + 0 * UNITS] = ta0 + g0;
    out[2 * BTU + base + 1 * UNITS] = ta1 + g1;
    out[2 * BTU + base + 2 * UNITS] = ta2 + g2;
    out[2 * BTU + base + 3 * UNITS] = ta3 + g3;
    out[2 * BTU + base + 4 * UNITS] = ta4 + g4;
    // v_sc
    out[3 * BTU + base + 0 * UNITS] = vsc0;
    out[3 * BTU + base + 1 * UNITS] = vsc1;
    out[3 * BTU + base + 2 * UNITS] = vsc2;
    out[3 * BTU + base + 3 * UNITS] = vsc3;
    out[3 * BTU + base + 4 * UNITS] = vsc4;
}

extern "C" void kernel_launch(void* const* d_in, const int* in_sizes, int n_in,
                              void* d_out, int out_size, void* d_ws, size_t ws_size,
                              hipStream_t stream) {
    const float* inputs = (const float*)d_in[0];
    const float* v0     = (const float*)d_in[1];
    const float* a0     = (const float*)d_in[2];
    const float* zbuf0  = (const float*)d_in[3];
    const float* wvals  = (const float*)d_in[4];
    const float* beta   = (const float*)d_in[5];
    const int*   cols   = (const int*)d_in[6];
    float* out = (float*)d_out;
    unsigned char* zbyte = (unsigned char*)d_ws;   // B*UNITS = 64 KB

    alif_pack<<<(BATCH * UNITS) / 256, 256, 0, stream>>>(zbuf0, zbyte);
    alif_main<<<256, 256, 0, stream>>>(inputs, v0, a0, wvals, beta, cols, zbyte, out);
}

// Round 4
// 79.803 us; speedup vs baseline: 1.0700x; 1.0700x over previous
//
#include <hip/hip_runtime.h>

#define UNITS 2048
#define KDIM  204
#define T     5
#define BATCH 32

#define BPB   8      // b-rows per block
#define ROWB  2064   // padded LDS row stride in bytes (16B aligned, 516 words ≡ 4 mod 32)

// decay powers, double-computed then rounded to float
#define PD1  0.951229424500714f     // exp(-0.05)
#define PD2  0.9048374180359595f    // exp(-0.10)
#define PD3  0.8607079764250578f    // exp(-0.15)
#define PD4  0.8187307530779818f    // exp(-0.20)
#define PD5  0.7788007830714049f    // exp(-0.25)
#define PA1  0.9950124791926823f    // exp(-0.005)
#define PA2  0.9900498337491681f    // exp(-0.010)
#define PA3  0.9851119396030626f    // exp(-0.015)
#define PA4  0.9801986733067553f    // exp(-0.020)
#define PA5  0.9753099120283326f    // exp(-0.025)
#define PAM1 1.0050125208594014f    // exp(+0.005)

// ---------------------------------------------------------------------------
// Pre-pass: pack z_buf0 (B,T,UNITS) float 0/1 into one byte per (b,u), bit t.
// ---------------------------------------------------------------------------
__global__ __launch_bounds__(256) void alif_pack(const float* __restrict__ zbuf,
                                                 unsigned char* __restrict__ zbyte) {
    int tid = blockIdx.x * 256 + threadIdx.x;   // 0 .. B*UNITS-1
    int u = tid & (UNITS - 1);
    int b = tid >> 11;                          // UNITS = 2^11
    unsigned v = 0;
#pragma unroll
    for (int t = 0; t < T; ++t) {
        float z = zbuf[((size_t)b * T + t) * UNITS + u];
        v |= (z > 0.5f ? 1u : 0u) << t;
    }
    zbyte[(size_t)b * UNITS + u] = (unsigned char)v;
}

// ---------------------------------------------------------------------------
// Main kernel v2: K-split x2 for occupancy (2 waves/SIMD instead of 1).
// Thread = (b, u, half). halves combine via __shfl_xor(.,16) in-wave.
// tid layout: bits0-3 = u(16), bit4 = half, bits5-7 = b_local(8).
// ---------------------------------------------------------------------------
#define ACC(zz, ww)                                          \
    acc0 = fmaf((float)((zz)      & 1u), (ww), acc0);        \
    acc1 = fmaf((float)(((zz)>>1) & 1u), (ww), acc1);        \
    acc2 = fmaf((float)(((zz)>>2) & 1u), (ww), acc2);        \
    acc3 = fmaf((float)(((zz)>>3) & 1u), (ww), acc3);        \
    acc4 = fmaf((float)(((zz)>>4) & 1u), (ww), acc4);

#define GATHER4(cc, ww)                                      \
    {   unsigned z0 = lds_z[rowoff + (cc).x];                \
        unsigned z1 = lds_z[rowoff + (cc).y];                \
        unsigned z2 = lds_z[rowoff + (cc).z];                \
        unsigned z3 = lds_z[rowoff + (cc).w];                \
        ACC(z0, (ww).x) ACC(z1, (ww).y)                      \
        ACC(z2, (ww).z) ACC(z3, (ww).w) }

__global__ __launch_bounds__(256) void alif_main(
    const float* __restrict__ inputs, const float* __restrict__ v0,
    const float* __restrict__ a0, const float* __restrict__ wv,
    const float* __restrict__ beta, const int* __restrict__ cols,
    const unsigned char* __restrict__ zbyte, float* __restrict__ out) {

    __shared__ unsigned char lds_z[BPB * ROWB];

    const int tid  = threadIdx.x;
    const int bx   = blockIdx.x;          // 0..511
    const int ublk = bx & 127;            // 128 u-blocks of 16
    const int bblk = bx >> 7;             // 4 b-blocks of 8
    const int u       = ublk * 16 + (tid & 15);
    const int h       = (tid >> 4) & 1;   // K-half
    const int b_local = tid >> 5;         // 0..7
    const int b       = bblk * BPB + b_local;

    // ---- stage 8 byte-rows (8 x 2048 B) into LDS with padded stride ----
    {
        const uint4* src = (const uint4*)(zbyte + (size_t)bblk * BPB * UNITS);
#pragma unroll
        for (int i = 0; i < 4; ++i) {
            int q = tid + 256 * i;        // 0..1023  (1024 uint4 = 16 KB)
            uint4 val = src[q];
            int row = q >> 7;             // 128 uint4 per 2048B row
            int col = (q & 127) << 4;     // byte offset in row
            *(uint4*)(&lds_z[row * ROWB + col]) = val;
        }
    }
    __syncthreads();

    const int rowoff = b_local * ROWB;

    // ---- i_rec: gather-MAC over this thread's K-half ----
    // h=0: int4 groups [0,26)  (k 0..103);  h=1: groups [26,51)  (k 104..203)
    const int4*   cp = (const int4*)(cols + (size_t)u * KDIM) + h * 26;
    const float4* wp = (const float4*)(wv + (size_t)u * KDIM) + h * 26;
    const int n = 26 - h;                 // 26 or 25 groups
    float acc0 = 0.f, acc1 = 0.f, acc2 = 0.f, acc3 = 0.f, acc4 = 0.f;

    int4   c0 = cp[0];  float4 w0 = wp[0];
    int4   c1 = cp[1];  float4 w1 = wp[1];
    for (int kk = 0; kk < n - 2; ++kk) {
        int4   cn = cp[kk + 2];
        float4 wn = wp[kk + 2];
        GATHER4(c0, w0)
        c0 = c1; w0 = w1; c1 = cn; w1 = wn;
    }
    GATHER4(c0, w0)
    GATHER4(c1, w1)

    // combine the two K-halves (pair lanes differ in bit4)
    acc0 += __shfl_xor(acc0, 16);
    acc1 += __shfl_xor(acc1, 16);
    acc2 += __shfl_xor(acc2, 16);
    acc3 += __shfl_xor(acc3, 16);
    acc4 += __shfl_xor(acc4, 16);

    // ---- ALIF update for T=5 (both halves compute; stores are split) ----
    const size_t base = ((size_t)b * T) * UNITS + u;
    float i0 = inputs[base + 0 * UNITS] + acc0;
    float i1 = inputs[base + 1 * UNITS] + acc1;
    float i2 = inputs[base + 2 * UNITS] + acc2;
    float i3 = inputs[base + 3 * UNITS] + acc3;
    float i4 = inputs[base + 4 * UNITS] + acc4;

    const float v0v = v0[(size_t)b * UNITS + u];
    const float a0v = a0[(size_t)b * UNITS + u];
    const float bet = beta[u];

    float f0 = i0;
    float f1 = fmaf(PD1, i0, i1);
    float f2 = PD2 * i0; f2 = fmaf(PD1, i1, f2); f2 += i2;
    float f3 = PD3 * i0; f3 = fmaf(PD2, i1, f3); f3 = fmaf(PD1, i2, f3); f3 += i3;
    float f4 = PD4 * i0; f4 = fmaf(PD3, i1, f4); f4 = fmaf(PD2, i2, f4);
    f4 = fmaf(PD1, i3, f4); f4 += i4;

    float tv0 = fmaf(PD1, v0v, f0);
    float tv1 = fmaf(PD2, v0v, f1);
    float tv2 = fmaf(PD3, v0v, f2);
    float tv3 = fmaf(PD4, v0v, f3);
    float tv4 = fmaf(PD5, v0v, f4);

    float ta0 = PA1 * a0v;
    float ta1 = PA2 * a0v;
    float ta2 = PA3 * a0v;
    float ta3 = PA4 * a0v;
    float ta4 = PA5 * a0v;

    float vsc0 = tv0 - bet * ta0 - 1.0f;
    float vsc1 = tv1 - bet * ta1 - 1.0f;
    float vsc2 = tv2 - bet * ta2 - 1.0f;
    float vsc3 = tv3 - bet * ta3 - 1.0f;
    float vsc4 = tv4 - bet * ta4 - 1.0f;

    unsigned zr = (vsc0 > 0.f ? 1u : 0u) | (vsc1 > 0.f ? 2u : 0u) |
                  (vsc2 > 0.f ? 4u : 0u) | (vsc3 > 0.f ? 8u : 0u) |
                  (vsc4 > 0.f ? 16u : 0u);
    const unsigned zob = lds_z[rowoff + u];

    float zf[T];
#pragma unroll
    for (int t = 0; t < T; ++t) {
        bool raw     = (zr >> t) & 1u;
        bool blocked = ((zr & ((1u << t) - 1u)) != 0u) || ((zob >> (t + 1)) != 0u);
        zf[t] = (raw && !blocked) ? 1.0f : 0.0f;
    }

    float r0 = zf[0];
    float r1 = fmaf(PD1, zf[0], zf[1]);
    float r2 = PD2 * zf[0]; r2 = fmaf(PD1, zf[1], r2); r2 += zf[2];
    float r3 = PD3 * zf[0]; r3 = fmaf(PD2, zf[1], r3); r3 = fmaf(PD1, zf[2], r3); r3 += zf[3];
    float r4 = PD4 * zf[0]; r4 = fmaf(PD3, zf[1], r4); r4 = fmaf(PD2, zf[2], r4);
    r4 = fmaf(PD1, zf[3], r4); r4 += zf[4];

    float g0 = PAM1 * zf[0];
    float g1 = zf[0]; g1 = fmaf(PAM1, zf[1], g1);
    float g2 = PA1 * zf[0]; g2 += zf[1]; g2 = fmaf(PAM1, zf[2], g2);
    float g3 = PA2 * zf[0]; g3 = fmaf(PA1, zf[1], g3); g3 += zf[2]; g3 = fmaf(PAM1, zf[3], g3);
    float g4 = PA3 * zf[0]; g4 = fmaf(PA2, zf[1], g4); g4 = fmaf(PA1, zf[2], g4);
    g4 += zf[3]; g4 = fmaf(PAM1, zf[4], g4);

    const size_t BTU = (size_t)BATCH * T * UNITS;
    if (h == 0) {
        // z
        out[0 * BTU + base + 0 * UNITS] = zf[0];
        out[0 * BTU + base + 1 * UNITS] = zf[1];
        out[0 * BTU + base + 2 * UNITS] = zf[2];
        out[0 * BTU + base + 3 * UNITS] = zf[3];
        out[0 * BTU + base + 4 * UNITS] = zf[4];
        // v_buf
        out[1 * BTU + base + 0 * UNITS] = tv0 - r0;
        out[1 * BTU + base + 1 * UNITS] = tv1 - r1;
        out[1 * BTU + base + 2 * UNITS] = tv2 - r2;
        out[1 * BTU + base + 3 * UNITS] = tv3 - r3;
        out[1 * BTU + base + 4 * UNITS] = tv4 - r4;
    } else {
        // a_buf
        out[2 * BTU + base + 0 * UNITS] = ta0 + g0;
        out[2 * BTU + base + 1 * UNITS] = ta1 + g1;
        out[2 * BTU + base + 2 * UNITS] = ta2 + g2;
        out[2 * BTU + base + 3 * UNITS] = ta3 + g3;
        out[2 * BTU + base + 4 * UNITS] = ta4 + g4;
        // v_sc
        out[3 * BTU + base + 0 * UNITS] = vsc0;
        out[3 * BTU + base + 1 * UNITS] = vsc1;
        out[3 * BTU + base + 2 * UNITS] = vsc2;
        out[3 * BTU + base + 3 * UNITS] = vsc3;
        out[3 * BTU + base + 4 * UNITS] = vsc4;
    }
}

extern "C" void kernel_launch(void* const* d_in, const int* in_sizes, int n_in,
                              void* d_out, int out_size, void* d_ws, size_t ws_size,
                              hipStream_t stream) {
    const float* inputs = (const float*)d_in[0];
    const float* v0     = (const float*)d_in[1];
    const float* a0     = (const float*)d_in[2];
    const float* zbuf0  = (const float*)d_in[3];
    const float* wvals  = (const float*)d_in[4];
    const float* beta   = (const float*)d_in[5];
    const int*   cols   = (const int*)d_in[6];
    float* out = (float*)d_out;
    unsigned char* zbyte = (unsigned char*)d_ws;   // B*UNITS = 64 KB

    alif_pack<<<(BATCH * UNITS) / 256, 256, 0, stream>>>(zbuf0, zbyte);
    alif_main<<<512, 256, 0, stream>>>(inputs, v0, a0, wvals, beta, cols, zbyte, out);
}